// Round 6
// baseline (2723.697 us; speedup 1.0000x reference)
//
#include <hip/hip_runtime.h>
#include <cstdint>

#define HH   512
#define HD2  1024
#define HD3  1536
#define EE   300
#define VV   32000
#define BB   32
#define LLn  64
#define TT   32

typedef unsigned short u16;
typedef __attribute__((ext_vector_type(8))) short short8;
typedef __attribute__((ext_vector_type(4))) float f32x4;

__device__ __forceinline__ float fast_tanh(float x) {
    float e = __expf(2.f * x);
    return 1.f - 2.f / (e + 1.f);
}
__device__ __forceinline__ float fast_sigmoid(float x) {
    float e = __expf(-x);
    return 1.f / (1.f + e);
}
__device__ __forceinline__ u16 f2bf(float x) {   // RNE
    union { float f; unsigned u; } v; v.f = x;
    unsigned r = v.u + 0x7FFFu + ((v.u >> 16) & 1u);
    return (u16)(r >> 16);
}
__device__ __forceinline__ u16 f_hi_trunc(float x) {
    union { float f; unsigned u; } v; v.f = x;
    return (u16)(v.u >> 16);
}
__device__ __forceinline__ u16 f_lo_trunc(float x) {
    union { float f; unsigned u; } v; v.f = x;
    float res = x - __uint_as_float(v.u & 0xFFFF0000u);   // exact
    union { float f; unsigned u; } w; w.f = res;
    return (u16)(w.u >> 16);
}
__device__ __forceinline__ float bf2f(u16 x) {
    union { unsigned u; float f; } v; v.u = ((unsigned)x) << 16;
    return v.f;
}
// Relaxed agent-scope atomic access: coherent at MALL, bypasses L1/L2,
// NO cache maintenance (the round-4/5 poison was acquire/release fences).
__device__ __forceinline__ float aload_f(const float* p) {
    unsigned v = __hip_atomic_load((unsigned*)p, __ATOMIC_RELAXED,
                                   __HIP_MEMORY_SCOPE_AGENT);
    return __uint_as_float(v);
}
__device__ __forceinline__ void astore_f(float* p, float x) {
    __hip_atomic_store((unsigned*)p, __float_as_uint(x), __ATOMIC_RELAXED,
                       __HIP_MEMORY_SCOPE_AGENT);
}

// ---------------------------------------------------------------------------
// prep_all: all fp32->bf16(hi/lo) conversions + gathers + W1 concat, fused
// into ONE launch. Segments by blockIdx.
// ---------------------------------------------------------------------------
__global__ __launch_bounds__(256) void prep_all(
    const float* __restrict__ enc_h, const float* __restrict__ U_a,
    const float* __restrict__ W_ctx, const float* __restrict__ W_emb,
    const float* __restrict__ embed, const int* __restrict__ tw,
    const float* __restrict__ W_hs, const float* __restrict__ W_a,
    const float* __restrict__ W_hzr,
    u16* __restrict__ EHhi, u16* __restrict__ EHlo,
    u16* __restrict__ UAhi, u16* __restrict__ UAlo,
    u16* __restrict__ WChi, u16* __restrict__ WClo,
    u16* __restrict__ WEhi, u16* __restrict__ WElo,
    u16* __restrict__ AGhi, u16* __restrict__ AGlo,
    u16* __restrict__ Whs16, float* __restrict__ W1cat)
{
    const int bid = blockIdx.x, tid = threadIdx.x;
    if (bid < 8192) {                         // enc_h 2048x1024
        int idx = bid * 256 + tid;
        float x = enc_h[idx];
        EHhi[idx] = f_hi_trunc(x); EHlo[idx] = f_lo_trunc(x);
    } else if (bid < 10240) {                 // U_a 1024x512
        int idx = (bid - 8192) * 256 + tid;
        float x = U_a[idx];
        UAhi[idx] = f_hi_trunc(x); UAlo[idx] = f_lo_trunc(x);
    } else if (bid < 16384) {                 // W_ctx 1024x1536
        int idx = (bid - 10240) * 256 + tid;
        float x = W_ctx[idx];
        WChi[idx] = f_hi_trunc(x); WClo[idx] = f_lo_trunc(x);
    } else if (bid < 18304) {                 // W_emb pad 320x1536 (300 valid)
        int idx = (bid - 16384) * 256 + tid;
        int r = idx / 1536, c = idx - r * 1536;
        float x = (r < EE) ? W_emb[(size_t)r * 1536 + c] : 0.f;
        WEhi[idx] = f_hi_trunc(x); WElo[idx] = f_lo_trunc(x);
    } else if (bid < 19584) {                 // embed gather 1024x320 (300 valid)
        int idx = (bid - 18304) * 256 + tid;
        int r = idx / 320, c = idx - r * 320;
        float x = (c < EE) ? embed[(size_t)tw[r] * EE + c] : 0.f;
        AGhi[idx] = f_hi_trunc(x); AGlo[idx] = f_lo_trunc(x);
    } else if (bid < 20608) {                 // W_hs -> bf16 512x512
        int idx = (bid - 19584) * 256 + tid;
        Whs16[idx] = f2bf(W_hs[idx]);
    } else {                                  // W1cat = [W_a | W_hzr] 512x1536
        int idx = (bid - 20608) * 256 + tid;  // bid < 23680
        int k = idx / 1536, c = idx - k * 1536;
        W1cat[idx] = (c < HH) ? W_a[(size_t)k * HH + c]
                              : W_hzr[(size_t)k * HD2 + (c - HH)];
    }
}

// ---------------------------------------------------------------------------
// transpose_conv: src fp32 [K][N] -> dst bf16 [N][dld] (RNE). For W_out.
// grid = (N/64, K/64), block = 256.
// ---------------------------------------------------------------------------
__global__ __launch_bounds__(256) void transpose_conv(
    const float* __restrict__ src, int K, int N, int dld,
    u16* __restrict__ dhi)
{
    __shared__ float t[64][65];
    const int nt = blockIdx.x, ktile = blockIdx.y, tid = threadIdx.x;
    const int n0 = nt * 64, k0 = ktile * 64;
#pragma unroll 4
    for (int i = 0; i < 16; i++) {
        int kr = i * 4 + (tid >> 6);
        int nc = tid & 63;
        t[kr][nc] = src[(size_t)(k0 + kr) * N + n0 + nc];
    }
    __syncthreads();
    const int n = tid >> 2, kc = (tid & 3) * 16;
    unsigned wh[8];
#pragma unroll
    for (int jj = 0; jj < 8; jj++) {
        float x0 = t[kc + 2 * jj][n], x1 = t[kc + 2 * jj + 1][n];
        wh[jj] = (unsigned)f2bf(x0) | ((unsigned)f2bf(x1) << 16);
    }
    u16* dh = dhi + (size_t)(n0 + n) * dld + k0 + kc;
    *(uint4*)(dh)     = (uint4){wh[0], wh[1], wh[2], wh[3]};
    *(uint4*)(dh + 8) = (uint4){wh[4], wh[5], wh[6], wh[7]};
}

// ---------------------------------------------------------------------------
// pre_mfma: C[M x N] = A @ W + bias via bf16 hi/lo x3 MFMA. Output fp32 or
// bf16(RNE). Tile 256(M) x 64(N), K staged 32. grid = (N/64, M/256).
// ---------------------------------------------------------------------------
template<int KSTEPS, bool BF16OUT>
__global__ __launch_bounds__(256) void pre_mfma(
    const u16* __restrict__ Ahi, const u16* __restrict__ Alo,
    const u16* __restrict__ Whi, const u16* __restrict__ Wlo,
    const float* __restrict__ bias, void* __restrict__ Cout, int N)
{
    __shared__ u16 ah[256 * 40], al[256 * 40];
    __shared__ u16 bh[64 * 40],  bl[64 * 40];
    const int nb = blockIdx.x, mb = blockIdx.y, tid = threadIdx.x;
    const int w = tid >> 6, ln = tid & 63;
    const int quad = ln >> 4, lm = ln & 15;
    const int n0 = nb * 64;
    const int K = KSTEPS * 32;

    f32x4 acc[4][4];
#pragma unroll
    for (int r = 0; r < 4; r++)
#pragma unroll
        for (int c = 0; c < 4; c++)
            acc[r][c] = (f32x4){0.f, 0.f, 0.f, 0.f};

    for (int kt = 0; kt < KSTEPS; kt++) {
        const int k0 = kt * 32;
        {
            const uint4* sh = (const uint4*)(Ahi + (size_t)(mb * 256 + tid) * K + k0);
            const uint4* sl = (const uint4*)(Alo + (size_t)(mb * 256 + tid) * K + k0);
            uint4 h0 = sh[0], h1 = sh[1], h2 = sh[2], h3 = sh[3];
            uint4 l0 = sl[0], l1 = sl[1], l2 = sl[2], l3 = sl[3];
            uint4* dh = (uint4*)(ah + tid * 40);
            dh[0] = h0; dh[1] = h1; dh[2] = h2; dh[3] = h3;
            uint4* dl = (uint4*)(al + tid * 40);
            dl[0] = l0; dl[1] = l1; dl[2] = l2; dl[3] = l3;
        }
        {
            const int kr = tid >> 3, c8 = (tid & 7) * 8;
            union { uint4 v; u16 u[8]; } uh, ul;
            uh.v = *(const uint4*)(Whi + (size_t)(k0 + kr) * N + n0 + c8);
            ul.v = *(const uint4*)(Wlo + (size_t)(k0 + kr) * N + n0 + c8);
#pragma unroll
            for (int jj = 0; jj < 8; jj++) {
                bh[(c8 + jj) * 40 + kr] = uh.u[jj];
                bl[(c8 + jj) * 40 + kr] = ul.u[jj];
            }
        }
        __syncthreads();
        short8 afh[4], afl[4], bfh[4], bfl[4];
#pragma unroll
        for (int r = 0; r < 4; r++) {
            afh[r] = *(const short8*)(ah + ((w * 4 + r) * 16 + lm) * 40 + quad * 8);
            afl[r] = *(const short8*)(al + ((w * 4 + r) * 16 + lm) * 40 + quad * 8);
        }
#pragma unroll
        for (int c = 0; c < 4; c++) {
            bfh[c] = *(const short8*)(bh + (c * 16 + lm) * 40 + quad * 8);
            bfl[c] = *(const short8*)(bl + (c * 16 + lm) * 40 + quad * 8);
        }
#pragma unroll
        for (int r = 0; r < 4; r++)
#pragma unroll
            for (int c = 0; c < 4; c++) {
                acc[r][c] = __builtin_amdgcn_mfma_f32_16x16x32_bf16(
                    afh[r], bfh[c], acc[r][c], 0, 0, 0);
                acc[r][c] = __builtin_amdgcn_mfma_f32_16x16x32_bf16(
                    afh[r], bfl[c], acc[r][c], 0, 0, 0);
                acc[r][c] = __builtin_amdgcn_mfma_f32_16x16x32_bf16(
                    afl[r], bfh[c], acc[r][c], 0, 0, 0);
            }
        __syncthreads();
    }
#pragma unroll
    for (int r = 0; r < 4; r++) {
        int row = mb * 256 + (w * 4 + r) * 16 + quad * 4;
#pragma unroll
        for (int c = 0; c < 4; c++) {
            int col = n0 + c * 16 + lm;
            float bo = bias[col];
#pragma unroll
            for (int q2 = 0; q2 < 4; q2++) {
                float val = acc[r][c][q2] + bo;
                if (BF16OUT)
                    ((u16*)Cout)[(size_t)(row + q2) * N + col] = f2bf(val);
                else
                    ((float*)Cout)[(size_t)(row + q2) * N + col] = val;
            }
        }
    }
}

// ---------------------------------------------------------------------------
// rnn_group: entire 32-step recurrence. grid = 256 (group b = blocks
// 8b..8b+7, j = bid&7), block = 256. ONE relaxed-atomic barrier per step.
// Phase A (k-split): block j computes partials over k in [64j,64j+64) for
// all 1536 gate cols, using its OWN s-slice from LDS (no communication).
// Phase B: sum partials (relaxed-atomic coalesced loads), redundant
// scores/softmax/rs, own 64-h slice of z/pst/gemm2/finalize.
// Weights are read with NORMAL cached loads and stay hot in L1/L2 —
// no fences anywhere.
// ---------------------------------------------------------------------------
__global__ __launch_bounds__(256) void rnn_group(
    const float* __restrict__ W1cat,     // [512][1536] fp32
    const u16* __restrict__ Uh16,        // [32*64][512]
    const u16* __restrict__ Gc16,        // [32*64][1536]
    const float* __restrict__ Ge,        // [1024][1536]
    const u16* __restrict__ Whs16,       // [512][512]
    const float* __restrict__ b_a, const float* __restrict__ v_w,
    const float* __restrict__ v_b, const float* __restrict__ b_hzr,
    const float* __restrict__ b_hs,
    const float* __restrict__ prev_s,
    float* __restrict__ sbuf0, float* __restrict__ sbuf1,
    float* __restrict__ partsA, float* __restrict__ partsB,  // [32][8][1536]
    u16* __restrict__ sqh, u16* __restrict__ sql,
    unsigned* __restrict__ bars)
{
    const int bid = blockIdx.x, tid = threadIdx.x;
    const int b = bid >> 3, j = bid & 7;
    const int ln = tid & 63, w = tid >> 6;

    __shared__ float s_own[64];
    __shared__ float o_lds[HH];
    __shared__ float sp_lds[HH];
    __shared__ float rs_s[HH];
    __shared__ float red[256];
    __shared__ float attn_s[LLn];
    __shared__ float zb_s[64], pst_s[64];

    unsigned* bar = bars + b * 64;   // 256-B padded per group

    // per-lane invariants
    float vw_r[8];
    {
        float4 v0 = *(const float4*)(v_w + ln * 8);
        float4 v1 = *(const float4*)(v_w + ln * 8 + 4);
        vw_r[0]=v0.x; vw_r[1]=v0.y; vw_r[2]=v0.z; vw_r[3]=v0.w;
        vw_r[4]=v1.x; vw_r[5]=v1.y; vw_r[6]=v1.z; vw_r[7]=v1.w;
    }
    const float vb = v_b[0];

    if (tid < 64) s_own[tid] = prev_s[(size_t)b * HH + j * 64 + tid];
    __syncthreads();

    for (int t = 0; t < TT; t++) {
        float* pw = ((t & 1) ? partsB : partsA)
                    + (size_t)b * (8 * HD3) + (size_t)j * HD3;
        const float* pr = ((t & 1) ? partsB : partsA) + (size_t)b * (8 * HD3);
        float* wbuf = (t & 1) ? sbuf1 : sbuf0;
        const float* rbuf = (t & 1) ? sbuf0 : sbuf1;   // valid for t>=1

        // ===== phase A: partials over own k-slice (exact fp32) =====
        {
            float acc0=0.f, acc1=0.f, acc2=0.f, acc3=0.f, acc4=0.f, acc5=0.f;
            const float* wb = W1cat + (size_t)(j * 64) * HD3 + tid;
            for (int k = 0; k < 64; k += 4) {
                float4 s4 = *(const float4*)(s_own + k);
#pragma unroll
                for (int kk = 0; kk < 4; kk++) {
                    const float* wr = wb + (size_t)(k + kk) * HD3;
                    float sv = (kk == 0) ? s4.x : (kk == 1) ? s4.y
                             : (kk == 2) ? s4.z : s4.w;
                    acc0 = fmaf(sv, wr[0],    acc0);
                    acc1 = fmaf(sv, wr[256],  acc1);
                    acc2 = fmaf(sv, wr[512],  acc2);
                    acc3 = fmaf(sv, wr[768],  acc3);
                    acc4 = fmaf(sv, wr[1024], acc4);
                    acc5 = fmaf(sv, wr[1280], acc5);
                }
            }
            astore_f(&pw[tid],        acc0);
            astore_f(&pw[tid + 256],  acc1);
            astore_f(&pw[tid + 512],  acc2);
            astore_f(&pw[tid + 768],  acc3);
            astore_f(&pw[tid + 1024], acc4);
            astore_f(&pw[tid + 1280], acc5);
        }
        // ===== one barrier per step (monotonic counter, no fences) =====
        asm volatile("s_waitcnt vmcnt(0)" ::: "memory");
        __syncthreads();
        if (tid == 0) {
            __hip_atomic_fetch_add(bar, 1u, __ATOMIC_RELAXED,
                                   __HIP_MEMORY_SCOPE_AGENT);
            const unsigned tgt = 8u * (unsigned)(t + 1);
            while (__hip_atomic_load(bar, __ATOMIC_RELAXED,
                                     __HIP_MEMORY_SCOPE_AGENT) < tgt)
                __builtin_amdgcn_s_sleep(1);
        }
        __syncthreads();
        asm volatile("" ::: "memory");

        // ===== phase B =====
        // b1: sum partials (coalesced atomic loads) + stage s_prev
        float r_g0 = 0.f, r_g1 = 0.f, z_g = 0.f;
        {
            float o0 = 0.f, o1 = 0.f;
#pragma unroll
            for (int p = 0; p < 8; p++) {
                const float* pp = pr + (size_t)p * HD3;
                o0   += aload_f(&pp[tid]);
                o1   += aload_f(&pp[tid + 256]);
                r_g0 += aload_f(&pp[HD2 + tid]);
                r_g1 += aload_f(&pp[HD2 + tid + 256]);
                if (tid < 64) z_g += aload_f(&pp[HH + j * 64 + tid]);
            }
            o_lds[tid]       = o0 + b_a[tid];
            o_lds[tid + 256] = o1 + b_a[tid + 256];
            float sp0, sp1;
            if (t == 0) {
                sp0 = prev_s[(size_t)b * HH + tid];
                sp1 = prev_s[(size_t)b * HH + tid + 256];
            } else {
                sp0 = aload_f(&rbuf[(size_t)b * HH + tid]);
                sp1 = aload_f(&rbuf[(size_t)b * HH + tid + 256]);
            }
            sp_lds[tid]       = sp0;
            sp_lds[tid + 256] = sp1;
        }
        __syncthreads();

        // scores: wave w handles l = w*16..w*16+15; lane owns 8 h
        {
            float o_r[8];
            float4 q0 = *(const float4*)(o_lds + ln * 8);
            float4 q1 = *(const float4*)(o_lds + ln * 8 + 4);
            o_r[0]=q0.x; o_r[1]=q0.y; o_r[2]=q0.z; o_r[3]=q0.w;
            o_r[4]=q1.x; o_r[5]=q1.y; o_r[6]=q1.z; o_r[7]=q1.w;
            for (int lt = 0; lt < 16; lt++) {
                const int l = w * 16 + lt;
                uint4 uv = *(const uint4*)(Uh16 + ((size_t)(b * LLn + l)) * HH + ln * 8);
                float acc;
                acc = fast_tanh(o_r[0] + __uint_as_float(uv.x << 16)) * vw_r[0];
                acc = fmaf(fast_tanh(o_r[1] + __uint_as_float(uv.x & 0xFFFF0000u)), vw_r[1], acc);
                acc = fmaf(fast_tanh(o_r[2] + __uint_as_float(uv.y << 16)),          vw_r[2], acc);
                acc = fmaf(fast_tanh(o_r[3] + __uint_as_float(uv.y & 0xFFFF0000u)), vw_r[3], acc);
                acc = fmaf(fast_tanh(o_r[4] + __uint_as_float(uv.z << 16)),          vw_r[4], acc);
                acc = fmaf(fast_tanh(o_r[5] + __uint_as_float(uv.z & 0xFFFF0000u)), vw_r[5], acc);
                acc = fmaf(fast_tanh(o_r[6] + __uint_as_float(uv.w << 16)),          vw_r[6], acc);
                acc = fmaf(fast_tanh(o_r[7] + __uint_as_float(uv.w & 0xFFFF0000u)), vw_r[7], acc);
                for (int o = 32; o > 0; o >>= 1) acc += __shfl_xor(acc, o);
                if (ln == 0) red[l] = acc;
            }
        }
        __syncthreads();
        if (tid < 64) {
            float v = red[tid] + vb;
            float m = v;
            for (int o = 32; o > 0; o >>= 1) m = fmaxf(m, __shfl_xor(m, o));
            float e = __expf(v - m);
            float s = e;
            for (int o = 32; o > 0; o >>= 1) s += __shfl_xor(s, o);
            attn_s[tid] = e / s;
        }
        __syncthreads();

        const float* ge = Ge + ((size_t)(b * TT + t)) * HD3;

        // rs (all threads, 2 h each) + z / pst (own slice)
        {
            const u16* gc = Gc16 + (size_t)b * LLn * HD3 + HH;
            float g1a = 0.f, g1b = 0.f;
#pragma unroll 4
            for (int l = 0; l < LLn; l++) {
                float a = attn_s[l];
                g1a = fmaf(a, bf2f(gc[(size_t)l * HD3 + tid]),       g1a);
                g1b = fmaf(a, bf2f(gc[(size_t)l * HD3 + tid + 256]), g1b);
            }
            float gra = b_hzr[HH + tid]       + ge[HH + tid]       + r_g0 + g1a;
            float grb = b_hzr[HH + tid + 256] + ge[HH + tid + 256] + r_g1 + g1b;
            rs_s[tid]       = fast_sigmoid(gra) * sp_lds[tid];
            rs_s[tid + 256] = fast_sigmoid(grb) * sp_lds[tid + 256];
        }
        if (tid < 64) {
            const int h = j * 64 + tid;
            const u16* gc = Gc16 + (size_t)b * LLn * HD3;
            float g0 = 0.f;
#pragma unroll 4
            for (int l = 0; l < LLn; l++)
                g0 = fmaf(attn_s[l], bf2f(gc[(size_t)l * HD3 + h]), g0);
            zb_s[tid] = fast_sigmoid(b_hzr[h] + ge[h] + z_g + g0);
        } else if (tid < 128) {
            const int c = tid - 64;
            const int h = j * 64 + c;
            const u16* gc = Gc16 + (size_t)b * LLn * HD3 + HD2;
            float g2 = 0.f;
#pragma unroll 4
            for (int l = 0; l < LLn; l++)
                g2 = fmaf(attn_s[l], bf2f(gc[(size_t)l * HD3 + h]), g2);
            pst_s[c] = ge[HD2 + h] + g2 + b_hs[h];
        }
        __syncthreads();

        // gemm2: col c = tid&63 of own 64-slice, k-quarter = wave
        {
            const int c = tid & 63, kq = tid >> 6;
            const u16* wp = Whs16 + (size_t)(kq * 128) * HH + j * 64 + c;
            const float* rp = rs_s + kq * 128;
            float a0 = 0.f, a1 = 0.f, a2 = 0.f, a3 = 0.f;
#pragma unroll 4
            for (int k = 0; k < 128; k += 4) {
                a0 = fmaf(rp[k + 0], bf2f(wp[(size_t)(k + 0) * HH]), a0);
                a1 = fmaf(rp[k + 1], bf2f(wp[(size_t)(k + 1) * HH]), a1);
                a2 = fmaf(rp[k + 2], bf2f(wp[(size_t)(k + 2) * HH]), a2);
                a3 = fmaf(rp[k + 3], bf2f(wp[(size_t)(k + 3) * HH]), a3);
            }
            red[tid] = (a0 + a1) + (a2 + a3);
        }
        __syncthreads();

        // finalize own slice
        if (tid < 64) {
            const int h = j * 64 + tid;
            float g2 = red[tid] + red[64 + tid] + red[128 + tid] + red[192 + tid];
            float st = fast_tanh(pst_s[tid] + g2);
            float sv = sp_lds[h];
            float sval = fmaf(zb_s[tid], st - sv, sv);
            s_own[tid] = sval;
            astore_f(&wbuf[(size_t)b * HH + h], sval);
            size_t off = ((size_t)b * TT + t) * HH + h;
            sqh[off] = f_hi_trunc(sval);
            sql[off] = f_lo_trunc(sval);
        }
        __syncthreads();
    }
}

// ---------------------------------------------------------------------------
// final_gemm: out[1024 x 32000] = s_seq(hi/lo bf16) @ Wt^T + b_out.
// grid = 500 (one 64-col Wt strip per block, staged ONCE in LDS, stride 520);
// internal mb loop covers all 1024 rows. A-fragments read direct from global.
// ---------------------------------------------------------------------------
__global__ __launch_bounds__(256) void final_gemm(
    const u16* __restrict__ Ahi, const u16* __restrict__ Alo,
    const u16* __restrict__ Wt, const float* __restrict__ b_out,
    float* __restrict__ out)
{
    __shared__ u16 b_lds[64 * 520];
    const int nb = blockIdx.x, tid = threadIdx.x;
    const int w = tid >> 6, ln = tid & 63;
    const int quad = ln >> 4, lm = ln & 15;
    const int n0 = nb * 64;

    for (int i = tid; i < 4096; i += 256) {
        int n = i >> 6, slot = i & 63;
        uint4 v = *(const uint4*)(Wt + (size_t)(n0 + n) * HH + slot * 8);
        *(uint4*)(b_lds + n * 520 + slot * 8) = v;
    }
    __syncthreads();

    for (int mb = 0; mb < 4; mb++) {
        f32x4 acc[4][4];
#pragma unroll
        for (int r = 0; r < 4; r++)
#pragma unroll
            for (int c = 0; c < 4; c++)
                acc[r][c] = (f32x4){0.f, 0.f, 0.f, 0.f};

        for (int kt = 0; kt < 16; kt++) {
            const int k0 = kt * 32;
            short8 afh[4], afl[4], bq[4];
#pragma unroll
            for (int r = 0; r < 4; r++) {
                const size_t row = (size_t)(mb * 256 + (w * 4 + r) * 16 + lm);
                afh[r] = *(const short8*)(Ahi + row * HH + k0 + quad * 8);
                afl[r] = *(const short8*)(Alo + row * HH + k0 + quad * 8);
            }
#pragma unroll
            for (int c = 0; c < 4; c++)
                bq[c] = *(const short8*)(b_lds + (c * 16 + lm) * 520 + k0 + quad * 8);
#pragma unroll
            for (int r = 0; r < 4; r++)
#pragma unroll
                for (int c = 0; c < 4; c++) {
                    acc[r][c] = __builtin_amdgcn_mfma_f32_16x16x32_bf16(
                        afh[r], bq[c], acc[r][c], 0, 0, 0);
                    acc[r][c] = __builtin_amdgcn_mfma_f32_16x16x32_bf16(
                        afl[r], bq[c], acc[r][c], 0, 0, 0);
                }
        }
#pragma unroll
        for (int r = 0; r < 4; r++) {
            int row = mb * 256 + (w * 4 + r) * 16 + quad * 4;
#pragma unroll
            for (int c = 0; c < 4; c++) {
                int col = n0 + c * 16 + lm;
                float bo = b_out[col];
#pragma unroll
                for (int qq = 0; qq < 4; qq++)
                    out[(size_t)(row + qq) * VV + col] = acc[r][c][qq] + bo;
            }
        }
    }
}

// ---------------------------------------------------------------------------
extern "C" void kernel_launch(void* const* d_in, const int* in_sizes, int n_in,
                              void* d_out, int out_size, void* d_ws, size_t ws_size,
                              hipStream_t stream)
{
    const float* enc_h  = (const float*)d_in[0];
    const float* prev_s = (const float*)d_in[1];
    const int*   tw     = (const int*)  d_in[2];
    const float* embed  = (const float*)d_in[3];
    const float* W_a    = (const float*)d_in[4];
    const float* b_a    = (const float*)d_in[5];
    const float* U_a    = (const float*)d_in[6];
    const float* b_Ua   = (const float*)d_in[7];
    const float* v_w    = (const float*)d_in[8];
    const float* v_b    = (const float*)d_in[9];
    const float* W_emb  = (const float*)d_in[10];
    const float* b_emb  = (const float*)d_in[11];
    const float* W_hzr  = (const float*)d_in[12];
    const float* b_hzr  = (const float*)d_in[13];
    const float* W_hs   = (const float*)d_in[14];
    const float* b_hs   = (const float*)d_in[15];
    const float* W_ctx  = (const float*)d_in[16];
    const float* b_ctx  = (const float*)d_in[17];
    const float* W_out  = (const float*)d_in[18];
    const float* b_out  = (const float*)d_in[19];
    float* out = (float*)d_out;

    float* ws = (float*)d_ws;
    unsigned* bars = (unsigned*)ws;  ws += 2048;     // 32 groups x 64 u32
    float* Ge     = ws;  ws += 1024 * 1536;
    float* W1cat  = ws;  ws += 512 * 1536;           // [W_a|W_hzr] fp32
    float* partsA = ws;  ws += 32 * 8 * 1536;
    float* partsB = ws;  ws += 32 * 8 * 1536;
    float* sbuf0  = ws;  ws += 32 * 512;
    float* sbuf1  = ws;  ws += 32 * 512;
    u16* Uh16 = (u16*)ws;  ws += (2048 * 512) / 2;
    u16* Gc16 = (u16*)ws;  ws += (2048 * 1536) / 2;
    u16* sqh  = (u16*)ws;  ws += (1024 * 512) / 2;
    u16* sql  = (u16*)ws;  ws += (1024 * 512) / 2;
    u16* EHhi = (u16*)ws;  ws += (2048 * 1024) / 2;
    u16* EHlo = (u16*)ws;  ws += (2048 * 1024) / 2;
    u16* UAhi = (u16*)ws;  ws += (1024 * 512) / 2;
    u16* UAlo = (u16*)ws;  ws += (1024 * 512) / 2;
    u16* WChi = (u16*)ws;  ws += (1024 * 1536) / 2;
    u16* WClo = (u16*)ws;  ws += (1024 * 1536) / 2;
    u16* WEhi = (u16*)ws;  ws += (320 * 1536) / 2;
    u16* WElo = (u16*)ws;  ws += (320 * 1536) / 2;
    u16* AGhi = (u16*)ws;  ws += (1024 * 320) / 2;
    u16* AGlo = (u16*)ws;  ws += (1024 * 320) / 2;
    u16* Wt   = (u16*)ws;  ws += (32000 * 512) / 2;
    u16* Whs16= (u16*)ws;  ws += (512 * 512) / 2;

    hipMemsetAsync(bars, 0, 8192, stream);

    prep_all<<<dim3(23680), 256, 0, stream>>>(
        enc_h, U_a, W_ctx, W_emb, embed, tw, W_hs, W_a, W_hzr,
        EHhi, EHlo, UAhi, UAlo, WChi, WClo, WEhi, WElo, AGhi, AGlo,
        Whs16, W1cat);

    transpose_conv<<<dim3(500, 8), 256, 0, stream>>>(W_out, 512, 32000, 512, Wt);

    pre_mfma<32, true ><<<dim3(8, 8),  256, 0, stream>>>(EHhi, EHlo, UAhi, UAlo, b_Ua,  Uh16, 512);
    pre_mfma<32, true ><<<dim3(24, 8), 256, 0, stream>>>(EHhi, EHlo, WChi, WClo, b_ctx, Gc16, 1536);
    pre_mfma<10, false><<<dim3(24, 4), 256, 0, stream>>>(AGhi, AGlo, WEhi, WElo, b_emb, Ge,   1536);

    rnn_group<<<dim3(256), 256, 0, stream>>>(
        W1cat, Uh16, Gc16, Ge, Whs16,
        b_a, v_w, v_b, b_hzr, b_hs,
        prev_s, sbuf0, sbuf1, partsA, partsB, sqh, sql, bars);

    final_gemm<<<dim3(500), 256, 0, stream>>>(sqh, sql, Wt, b_out, out);
}

// Round 7
// 2650.926 us; speedup vs baseline: 1.0275x; 1.0275x over previous
//
#include <hip/hip_runtime.h>
#include <cstdint>

#define HH   512
#define HD2  1024
#define HD3  1536
#define EE   300
#define VV   32000
#define BB   32
#define LLn  64
#define TT   32

typedef unsigned short u16;
typedef __attribute__((ext_vector_type(8))) short short8;
typedef __attribute__((ext_vector_type(4))) float f32x4;

__device__ __forceinline__ float fast_tanh(float x) {
    float e = __expf(2.f * x);
    return 1.f - 2.f / (e + 1.f);
}
__device__ __forceinline__ float fast_sigmoid(float x) {
    float e = __expf(-x);
    return 1.f / (1.f + e);
}
__device__ __forceinline__ u16 f2bf(float x) {   // RNE
    union { float f; unsigned u; } v; v.f = x;
    unsigned r = v.u + 0x7FFFu + ((v.u >> 16) & 1u);
    return (u16)(r >> 16);
}
__device__ __forceinline__ u16 f_hi_trunc(float x) {
    union { float f; unsigned u; } v; v.f = x;
    return (u16)(v.u >> 16);
}
__device__ __forceinline__ u16 f_lo_trunc(float x) {
    union { float f; unsigned u; } v; v.f = x;
    float res = x - __uint_as_float(v.u & 0xFFFF0000u);   // exact
    union { float f; unsigned u; } w; w.f = res;
    return (u16)(w.u >> 16);
}
__device__ __forceinline__ float bf2f(u16 x) {
    union { unsigned u; float f; } v; v.u = ((unsigned)x) << 16;
    return v.f;
}

// ---------------------------------------------------------------------------
// prep_all: conversions + gathers + W1q packing + combined bias, one launch.
// W1q[k][j] = float4{ W_a[k][j], W_hzr[k][j], W_hzr[k][512+j], 0 } so the
// step kernel gets all 3 gate weights for (k, j) in ONE dwordx4.
// ---------------------------------------------------------------------------
__global__ __launch_bounds__(256) void prep_all(
    const float* __restrict__ enc_h, const float* __restrict__ U_a,
    const float* __restrict__ W_ctx, const float* __restrict__ W_emb,
    const float* __restrict__ embed, const int* __restrict__ tw,
    const float* __restrict__ W_a, const float* __restrict__ W_hzr,
    const float* __restrict__ b_Ua, const float* __restrict__ b_a,
    u16* __restrict__ EHhi, u16* __restrict__ EHlo,
    u16* __restrict__ UAhi, u16* __restrict__ UAlo,
    u16* __restrict__ WChi, u16* __restrict__ WClo,
    u16* __restrict__ WEhi, u16* __restrict__ WElo,
    u16* __restrict__ AGhi, u16* __restrict__ AGlo,
    float* __restrict__ W1q, float* __restrict__ bUa2)
{
    const int bid = blockIdx.x, tid = threadIdx.x;
    if (bid < 8192) {                         // enc_h 2048x1024
        int idx = bid * 256 + tid;
        float x = enc_h[idx];
        EHhi[idx] = f_hi_trunc(x); EHlo[idx] = f_lo_trunc(x);
    } else if (bid < 10240) {                 // U_a 1024x512
        int idx = (bid - 8192) * 256 + tid;
        float x = U_a[idx];
        UAhi[idx] = f_hi_trunc(x); UAlo[idx] = f_lo_trunc(x);
    } else if (bid < 16384) {                 // W_ctx 1024x1536
        int idx = (bid - 10240) * 256 + tid;
        float x = W_ctx[idx];
        WChi[idx] = f_hi_trunc(x); WClo[idx] = f_lo_trunc(x);
    } else if (bid < 18304) {                 // W_emb pad 320x1536 (300 valid)
        int idx = (bid - 16384) * 256 + tid;
        int r = idx / 1536, c = idx - r * 1536;
        float x = (r < EE) ? W_emb[(size_t)r * 1536 + c] : 0.f;
        WEhi[idx] = f_hi_trunc(x); WElo[idx] = f_lo_trunc(x);
    } else if (bid < 19584) {                 // embed gather 1024x320 (300 valid)
        int idx = (bid - 18304) * 256 + tid;
        int r = idx / 320, c = idx - r * 320;
        float x = (c < EE) ? embed[(size_t)tw[r] * EE + c] : 0.f;
        AGhi[idx] = f_hi_trunc(x); AGlo[idx] = f_lo_trunc(x);
    } else if (bid < 20608) {                 // W1q pack 512x512
        int idx = (bid - 19584) * 256 + tid;
        int k = idx >> 9, j = idx & 511;
        float4 v;
        v.x = W_a[(size_t)k * HH + j];
        v.y = W_hzr[(size_t)k * HD2 + j];
        v.z = W_hzr[(size_t)k * HD2 + HH + j];
        v.w = 0.f;
        *(float4*)(W1q + (size_t)idx * 4) = v;
    } else {                                  // bUa2 = b_Ua + b_a (512)
        int idx = (bid - 20608) * 256 + tid;
        if (idx < HH) bUa2[idx] = b_Ua[idx] + b_a[idx];
    }
}

// ---------------------------------------------------------------------------
// transpose_conv: W_out fp32 [512][32000] -> Wt bf16 [32000][512] (RNE).
// grid = (N/64, K/64), block = 256.
// ---------------------------------------------------------------------------
__global__ __launch_bounds__(256) void transpose_conv(
    const float* __restrict__ src, int K, int N, int dld,
    u16* __restrict__ dhi)
{
    __shared__ float t[64][65];
    const int nt = blockIdx.x, ktile = blockIdx.y, tid = threadIdx.x;
    const int n0 = nt * 64, k0 = ktile * 64;
#pragma unroll 4
    for (int i = 0; i < 16; i++) {
        int kr = i * 4 + (tid >> 6);
        int nc = tid & 63;
        t[kr][nc] = src[(size_t)(k0 + kr) * N + n0 + nc];
    }
    __syncthreads();
    const int n = tid >> 2, kc = (tid & 3) * 16;
    unsigned wh[8];
#pragma unroll
    for (int jj = 0; jj < 8; jj++) {
        float x0 = t[kc + 2 * jj][n], x1 = t[kc + 2 * jj + 1][n];
        wh[jj] = (unsigned)f2bf(x0) | ((unsigned)f2bf(x1) << 16);
    }
    u16* dh = dhi + (size_t)(n0 + n) * dld + k0 + kc;
    *(uint4*)(dh)     = (uint4){wh[0], wh[1], wh[2], wh[3]};
    *(uint4*)(dh + 8) = (uint4){wh[4], wh[5], wh[6], wh[7]};
}

// ---------------------------------------------------------------------------
// pre_mfma: C[M x N] = A @ W + bias via bf16 hi/lo x3 MFMA. Output fp32 or
// bf16(RNE). Tile 256(M) x 64(N), K staged 32. grid = (N/64, M/256).
// ---------------------------------------------------------------------------
template<int KSTEPS, bool BF16OUT>
__global__ __launch_bounds__(256) void pre_mfma(
    const u16* __restrict__ Ahi, const u16* __restrict__ Alo,
    const u16* __restrict__ Whi, const u16* __restrict__ Wlo,
    const float* __restrict__ bias, void* __restrict__ Cout, int N)
{
    __shared__ u16 ah[256 * 40], al[256 * 40];
    __shared__ u16 bh[64 * 40],  bl[64 * 40];
    const int nb = blockIdx.x, mb = blockIdx.y, tid = threadIdx.x;
    const int w = tid >> 6, ln = tid & 63;
    const int quad = ln >> 4, lm = ln & 15;
    const int n0 = nb * 64;
    const int K = KSTEPS * 32;

    f32x4 acc[4][4];
#pragma unroll
    for (int r = 0; r < 4; r++)
#pragma unroll
        for (int c = 0; c < 4; c++)
            acc[r][c] = (f32x4){0.f, 0.f, 0.f, 0.f};

    for (int kt = 0; kt < KSTEPS; kt++) {
        const int k0 = kt * 32;
        {
            const uint4* sh = (const uint4*)(Ahi + (size_t)(mb * 256 + tid) * K + k0);
            const uint4* sl = (const uint4*)(Alo + (size_t)(mb * 256 + tid) * K + k0);
            uint4 h0 = sh[0], h1 = sh[1], h2 = sh[2], h3 = sh[3];
            uint4 l0 = sl[0], l1 = sl[1], l2 = sl[2], l3 = sl[3];
            uint4* dh = (uint4*)(ah + tid * 40);
            dh[0] = h0; dh[1] = h1; dh[2] = h2; dh[3] = h3;
            uint4* dl = (uint4*)(al + tid * 40);
            dl[0] = l0; dl[1] = l1; dl[2] = l2; dl[3] = l3;
        }
        {
            const int kr = tid >> 3, c8 = (tid & 7) * 8;
            union { uint4 v; u16 u[8]; } uh, ul;
            uh.v = *(const uint4*)(Whi + (size_t)(k0 + kr) * N + n0 + c8);
            ul.v = *(const uint4*)(Wlo + (size_t)(k0 + kr) * N + n0 + c8);
#pragma unroll
            for (int jj = 0; jj < 8; jj++) {
                bh[(c8 + jj) * 40 + kr] = uh.u[jj];
                bl[(c8 + jj) * 40 + kr] = ul.u[jj];
            }
        }
        __syncthreads();
        short8 afh[4], afl[4], bfh[4], bfl[4];
#pragma unroll
        for (int r = 0; r < 4; r++) {
            afh[r] = *(const short8*)(ah + ((w * 4 + r) * 16 + lm) * 40 + quad * 8);
            afl[r] = *(const short8*)(al + ((w * 4 + r) * 16 + lm) * 40 + quad * 8);
        }
#pragma unroll
        for (int c = 0; c < 4; c++) {
            bfh[c] = *(const short8*)(bh + (c * 16 + lm) * 40 + quad * 8);
            bfl[c] = *(const short8*)(bl + (c * 16 + lm) * 40 + quad * 8);
        }
#pragma unroll
        for (int r = 0; r < 4; r++)
#pragma unroll
            for (int c = 0; c < 4; c++) {
                acc[r][c] = __builtin_amdgcn_mfma_f32_16x16x32_bf16(
                    afh[r], bfh[c], acc[r][c], 0, 0, 0);
                acc[r][c] = __builtin_amdgcn_mfma_f32_16x16x32_bf16(
                    afh[r], bfl[c], acc[r][c], 0, 0, 0);
                acc[r][c] = __builtin_amdgcn_mfma_f32_16x16x32_bf16(
                    afl[r], bfh[c], acc[r][c], 0, 0, 0);
            }
        __syncthreads();
    }
#pragma unroll
    for (int r = 0; r < 4; r++) {
        int row = mb * 256 + (w * 4 + r) * 16 + quad * 4;
#pragma unroll
        for (int c = 0; c < 4; c++) {
            int col = n0 + c * 16 + lm;
            float bo = bias[col];
#pragma unroll
            for (int q2 = 0; q2 < 4; q2++) {
                float val = acc[r][c][q2] + bo;
                if (BF16OUT)
                    ((u16*)Cout)[(size_t)(row + q2) * N + col] = f2bf(val);
                else
                    ((float*)Cout)[(size_t)(row + q2) * N + col] = val;
            }
        }
    }
}

// ---------------------------------------------------------------------------
// step_fused: ONE kernel per timestep. grid = 32 (one block per batch),
// block = 512 (8 waves). Thread tid owns h = tid end-to-end:
//   phase A: (outs, z, r) partials from packed W1q (1 dwordx4 per k)
//   scores/softmax: wave-parallel over l, lanes over h
//   gcs: 3 bf16 gathers per l (z, r, pst columns)
//   gemm2: raw fp32 W_hs column tid over rs (LDS)
//   finalize: all in-register; write s_out + hi/lo bf16 sseq row.
// No cross-block communication: launch boundary is the only sync.
// ---------------------------------------------------------------------------
__global__ __launch_bounds__(512) void step_fused(
    const float* __restrict__ W1q,       // [512k][512j] float4
    const u16* __restrict__ Uh16,        // [32*64][512] bf16 (b_Ua+b_a baked)
    const u16* __restrict__ Gc16,        // [32*64][1536] bf16 (b_ctx baked)
    const float* __restrict__ Ge,        // [1024][1536] fp32 (b_emb baked)
    const float* __restrict__ W_hs,      // [512][512] fp32 (raw input)
    const float* __restrict__ b_hzr, const float* __restrict__ b_hs,
    const float* __restrict__ v_w, const float* __restrict__ v_b,
    const float* __restrict__ s_in, float* __restrict__ s_out,
    u16* __restrict__ sqh, u16* __restrict__ sql, int t)
{
    const int b = blockIdx.x, tid = threadIdx.x;
    const int ln = tid & 63, w = tid >> 6;
    __shared__ float s_lds[HH];
    __shared__ float outs_s[HH];
    __shared__ float rs_s[HH];
    __shared__ float red[LLn];
    __shared__ float attn_s[LLn];

    s_lds[tid] = s_in[(size_t)b * HH + tid];
    __syncthreads();

    // ===== phase A: gates matvec, 3 cols per thread via packed float4 =====
    float aO0 = 0.f, aO1 = 0.f, aZ0 = 0.f, aZ1 = 0.f, aR0 = 0.f, aR1 = 0.f;
    {
        const float4* wq = (const float4*)W1q + tid;   // row stride 512 float4
        for (int k = 0; k < HH; k += 4) {
            float4 s4 = *(const float4*)(s_lds + k);
            float4 w0 = wq[(size_t)(k + 0) * HH];
            float4 w1 = wq[(size_t)(k + 1) * HH];
            float4 w2 = wq[(size_t)(k + 2) * HH];
            float4 w3 = wq[(size_t)(k + 3) * HH];
            aO0 = fmaf(s4.x, w0.x, aO0); aZ0 = fmaf(s4.x, w0.y, aZ0); aR0 = fmaf(s4.x, w0.z, aR0);
            aO1 = fmaf(s4.y, w1.x, aO1); aZ1 = fmaf(s4.y, w1.y, aZ1); aR1 = fmaf(s4.y, w1.z, aR1);
            aO0 = fmaf(s4.z, w2.x, aO0); aZ0 = fmaf(s4.z, w2.y, aZ0); aR0 = fmaf(s4.z, w2.z, aR0);
            aO1 = fmaf(s4.w, w3.x, aO1); aZ1 = fmaf(s4.w, w3.y, aZ1); aR1 = fmaf(s4.w, w3.z, aR1);
        }
    }
    outs_s[tid] = aO0 + aO1;          // b_a baked into Uh16 bias
    const float accZ = aZ0 + aZ1, accR = aR0 + aR1;
    __syncthreads();

    // ===== scores: wave w -> l = w*8..w*8+7; lane owns 8 h =====
    {
        float vw_r[8], o_r[8];
        {
            float4 v0 = *(const float4*)(v_w + ln * 8);
            float4 v1 = *(const float4*)(v_w + ln * 8 + 4);
            vw_r[0]=v0.x; vw_r[1]=v0.y; vw_r[2]=v0.z; vw_r[3]=v0.w;
            vw_r[4]=v1.x; vw_r[5]=v1.y; vw_r[6]=v1.z; vw_r[7]=v1.w;
            float4 q0 = *(const float4*)(outs_s + ln * 8);
            float4 q1 = *(const float4*)(outs_s + ln * 8 + 4);
            o_r[0]=q0.x; o_r[1]=q0.y; o_r[2]=q0.z; o_r[3]=q0.w;
            o_r[4]=q1.x; o_r[5]=q1.y; o_r[6]=q1.z; o_r[7]=q1.w;
        }
#pragma unroll
        for (int lt = 0; lt < 8; lt++) {
            const int l = w * 8 + lt;
            uint4 uv = *(const uint4*)(Uh16 + ((size_t)(b * LLn + l)) * HH + ln * 8);
            float acc;
            acc = fast_tanh(o_r[0] + __uint_as_float(uv.x << 16)) * vw_r[0];
            acc = fmaf(fast_tanh(o_r[1] + __uint_as_float(uv.x & 0xFFFF0000u)), vw_r[1], acc);
            acc = fmaf(fast_tanh(o_r[2] + __uint_as_float(uv.y << 16)),          vw_r[2], acc);
            acc = fmaf(fast_tanh(o_r[3] + __uint_as_float(uv.y & 0xFFFF0000u)), vw_r[3], acc);
            acc = fmaf(fast_tanh(o_r[4] + __uint_as_float(uv.z << 16)),          vw_r[4], acc);
            acc = fmaf(fast_tanh(o_r[5] + __uint_as_float(uv.z & 0xFFFF0000u)), vw_r[5], acc);
            acc = fmaf(fast_tanh(o_r[6] + __uint_as_float(uv.w << 16)),          vw_r[6], acc);
            acc = fmaf(fast_tanh(o_r[7] + __uint_as_float(uv.w & 0xFFFF0000u)), vw_r[7], acc);
            for (int o = 32; o > 0; o >>= 1) acc += __shfl_xor(acc, o);
            if (ln == 0) red[l] = acc;
        }
    }
    __syncthreads();
    if (tid < 64) {
        float v = red[tid] + v_b[0];
        float m = v;
        for (int o = 32; o > 0; o >>= 1) m = fmaxf(m, __shfl_xor(m, o));
        float e = __expf(v - m);
        float s = e;
        for (int o = 32; o > 0; o >>= 1) s += __shfl_xor(s, o);
        attn_s[tid] = e / s;
    }
    __syncthreads();

    // ===== gcs + gate nonlinearities (thread owns cols tid/512+tid/1024+tid)
    float gz = 0.f, gr = 0.f, gp = 0.f;
    {
        const u16* gcb = Gc16 + (size_t)b * LLn * HD3;
#pragma unroll 4
        for (int l = 0; l < LLn; l++) {
            float a = attn_s[l];
            const u16* g = gcb + (size_t)l * HD3;
            gz = fmaf(a, bf2f(g[tid]),        gz);
            gr = fmaf(a, bf2f(g[HH + tid]),   gr);
            gp = fmaf(a, bf2f(g[HD2 + tid]),  gp);
        }
    }
    const float* ge = Ge + ((size_t)(b * TT + t)) * HD3;
    const float sv = s_lds[tid];
    const float z = fast_sigmoid(ge[tid]      + accZ + b_hzr[tid]      + gz);
    const float r = fast_sigmoid(ge[HH + tid] + accR + b_hzr[HH + tid] + gr);
    rs_s[tid] = r * sv;
    const float pst = ge[HD2 + tid] + gp + b_hs[tid];
    __syncthreads();

    // ===== gemm2: col tid over all 512 k, raw fp32 W_hs =====
    float g0 = 0.f, g1 = 0.f, g2 = 0.f, g3 = 0.f;
    {
        const float* wp = W_hs + tid;
        for (int k = 0; k < HH; k += 4) {
            float4 r4 = *(const float4*)(rs_s + k);
            g0 = fmaf(r4.x, wp[(size_t)(k + 0) * HH], g0);
            g1 = fmaf(r4.y, wp[(size_t)(k + 1) * HH], g1);
            g2 = fmaf(r4.z, wp[(size_t)(k + 2) * HH], g2);
            g3 = fmaf(r4.w, wp[(size_t)(k + 3) * HH], g3);
        }
    }
    const float st = fast_tanh(pst + (g0 + g1) + (g2 + g3));
    const float sn = fmaf(z, st - sv, sv);
    s_out[(size_t)b * HH + tid] = sn;
    const size_t off = ((size_t)b * TT + t) * HH + tid;
    sqh[off] = f_hi_trunc(sn);
    sql[off] = f_lo_trunc(sn);
}

// ---------------------------------------------------------------------------
// final_gemm: out[1024 x 32000] = s_seq(hi/lo bf16) @ Wt^T + b_out.
// grid = 500 (one 64-col Wt strip per block, staged ONCE in LDS, stride 520
// = 2-way bank aliasing only); internal mb loop; A direct from global.
// ---------------------------------------------------------------------------
__global__ __launch_bounds__(256) void final_gemm(
    const u16* __restrict__ Ahi, const u16* __restrict__ Alo,
    const u16* __restrict__ Wt, const float* __restrict__ b_out,
    float* __restrict__ out)
{
    __shared__ u16 b_lds[64 * 520];
    const int nb = blockIdx.x, tid = threadIdx.x;
    const int w = tid >> 6, ln = tid & 63;
    const int quad = ln >> 4, lm = ln & 15;
    const int n0 = nb * 64;

    for (int i = tid; i < 4096; i += 256) {
        int n = i >> 6, slot = i & 63;
        uint4 v = *(const uint4*)(Wt + (size_t)(n0 + n) * HH + slot * 8);
        *(uint4*)(b_lds + n * 520 + slot * 8) = v;
    }
    __syncthreads();

    for (int mb = 0; mb < 4; mb++) {
        f32x4 acc[4][4];
#pragma unroll
        for (int r = 0; r < 4; r++)
#pragma unroll
            for (int c = 0; c < 4; c++)
                acc[r][c] = (f32x4){0.f, 0.f, 0.f, 0.f};

        for (int kt = 0; kt < 16; kt++) {
            const int k0 = kt * 32;
            short8 afh[4], afl[4], bq[4];
#pragma unroll
            for (int r = 0; r < 4; r++) {
                const size_t row = (size_t)(mb * 256 + (w * 4 + r) * 16 + lm);
                afh[r] = *(const short8*)(Ahi + row * HH + k0 + quad * 8);
                afl[r] = *(const short8*)(Alo + row * HH + k0 + quad * 8);
            }
#pragma unroll
            for (int c = 0; c < 4; c++)
                bq[c] = *(const short8*)(b_lds + (c * 16 + lm) * 520 + k0 + quad * 8);
#pragma unroll
            for (int r = 0; r < 4; r++)
#pragma unroll
                for (int c = 0; c < 4; c++) {
                    acc[r][c] = __builtin_amdgcn_mfma_f32_16x16x32_bf16(
                        afh[r], bq[c], acc[r][c], 0, 0, 0);
                    acc[r][c] = __builtin_amdgcn_mfma_f32_16x16x32_bf16(
                        afl[r], bq[c], acc[r][c], 0, 0, 0);
                }
        }
#pragma unroll
        for (int r = 0; r < 4; r++) {
            int row = mb * 256 + (w * 4 + r) * 16 + quad * 4;
#pragma unroll
            for (int c = 0; c < 4; c++) {
                int col = n0 + c * 16 + lm;
                float bo = b_out[col];
#pragma unroll
                for (int qq = 0; qq < 4; qq++)
                    out[(size_t)(row + qq) * VV + col] = acc[r][c][qq] + bo;
            }
        }
    }
}

// ---------------------------------------------------------------------------
extern "C" void kernel_launch(void* const* d_in, const int* in_sizes, int n_in,
                              void* d_out, int out_size, void* d_ws, size_t ws_size,
                              hipStream_t stream)
{
    const float* enc_h  = (const float*)d_in[0];
    const float* prev_s = (const float*)d_in[1];
    const int*   tw     = (const int*)  d_in[2];
    const float* embed  = (const float*)d_in[3];
    const float* W_a    = (const float*)d_in[4];
    const float* b_a    = (const float*)d_in[5];
    const float* U_a    = (const float*)d_in[6];
    const float* b_Ua   = (const float*)d_in[7];
    const float* v_w    = (const float*)d_in[8];
    const float* v_b    = (const float*)d_in[9];
    const float* W_emb  = (const float*)d_in[10];
    const float* b_emb  = (const float*)d_in[11];
    const float* W_hzr  = (const float*)d_in[12];
    const float* b_hzr  = (const float*)d_in[13];
    const float* W_hs   = (const float*)d_in[14];
    const float* b_hs   = (const float*)d_in[15];
    const float* W_ctx  = (const float*)d_in[16];
    const float* b_ctx  = (const float*)d_in[17];
    const float* W_out  = (const float*)d_in[18];
    const float* b_out  = (const float*)d_in[19];
    float* out = (float*)d_out;

    float* ws = (float*)d_ws;
    float* Ge     = ws;  ws += 1024 * 1536;
    float* W1q    = ws;  ws += 512 * 512 * 4;        // packed gate weights
    float* bUa2   = ws;  ws += 512;
    float* s0     = ws;  ws += 32 * 512;
    float* s1     = ws;  ws += 32 * 512;
    u16* Uh16 = (u16*)ws;  ws += (2048 * 512) / 2;
    u16* Gc16 = (u16*)ws;  ws += (2048 * 1536) / 2;
    u16* sqh  = (u16*)ws;  ws += (1024 * 512) / 2;
    u16* sql  = (u16*)ws;  ws += (1024 * 512) / 2;
    u16* EHhi = (u16*)ws;  ws += (2048 * 1024) / 2;
    u16* EHlo = (u16*)ws;  ws += (2048 * 1024) / 2;
    u16* UAhi = (u16*)ws;  ws += (1024 * 512) / 2;
    u16* UAlo = (u16*)ws;  ws += (1024 * 512) / 2;
    u16* WChi = (u16*)ws;  ws += (1024 * 1536) / 2;
    u16* WClo = (u16*)ws;  ws += (1024 * 1536) / 2;
    u16* WEhi = (u16*)ws;  ws += (320 * 1536) / 2;
    u16* WElo = (u16*)ws;  ws += (320 * 1536) / 2;
    u16* AGhi = (u16*)ws;  ws += (1024 * 320) / 2;
    u16* AGlo = (u16*)ws;  ws += (1024 * 320) / 2;
    u16* Wt   = (u16*)ws;  ws += (32000 * 512) / 2;

    prep_all<<<dim3(20610), 256, 0, stream>>>(
        enc_h, U_a, W_ctx, W_emb, embed, tw, W_a, W_hzr, b_Ua, b_a,
        EHhi, EHlo, UAhi, UAlo, WChi, WClo, WEhi, WElo, AGhi, AGlo,
        W1q, bUa2);

    transpose_conv<<<dim3(500, 8), 256, 0, stream>>>(W_out, 512, 32000, 512, Wt);

    pre_mfma<32, true ><<<dim3(8, 8),  256, 0, stream>>>(EHhi, EHlo, UAhi, UAlo, bUa2,  Uh16, 512);
    pre_mfma<32, true ><<<dim3(24, 8), 256, 0, stream>>>(EHhi, EHlo, WChi, WClo, b_ctx, Gc16, 1536);
    pre_mfma<10, false><<<dim3(24, 4), 256, 0, stream>>>(AGhi, AGlo, WEhi, WElo, b_emb, Ge,   1536);

    for (int t = 0; t < TT; t++) {
        const float* s_in = (t == 0) ? prev_s : ((t & 1) ? s0 : s1);
        float* s_out = (t & 1) ? s1 : s0;
        step_fused<<<dim3(32), 512, 0, stream>>>(
            W1q, Uh16, Gc16, Ge, W_hs, b_hzr, b_hs, v_w, v_b,
            s_in, s_out, sqh, sql, t);
    }

    final_gemm<<<dim3(500), 256, 0, stream>>>(sqh, sql, Wt, b_out, out);
}

// Round 8
// 1515.895 us; speedup vs baseline: 1.7968x; 1.7488x over previous
//
#include <hip/hip_runtime.h>
#include <cstdint>

#define HH   512
#define HD2  1024
#define HD3  1536
#define EE   300
#define VV   32000
#define BB   32
#define LLn  64
#define TT   32

typedef unsigned short u16;
typedef __attribute__((ext_vector_type(8))) short short8;
typedef __attribute__((ext_vector_type(4))) float f32x4;

__device__ __forceinline__ float fast_tanh(float x) {
    float e = __expf(2.f * x);
    return 1.f - 2.f / (e + 1.f);
}
__device__ __forceinline__ float fast_sigmoid(float x) {
    float e = __expf(-x);
    return 1.f / (1.f + e);
}
__device__ __forceinline__ u16 f2bf(float x) {   // RNE
    union { float f; unsigned u; } v; v.f = x;
    unsigned r = v.u + 0x7FFFu + ((v.u >> 16) & 1u);
    return (u16)(r >> 16);
}
__device__ __forceinline__ u16 f_hi_trunc(float x) {
    union { float f; unsigned u; } v; v.f = x;
    return (u16)(v.u >> 16);
}
__device__ __forceinline__ u16 f_lo_trunc(float x) {
    union { float f; unsigned u; } v; v.f = x;
    float res = x - __uint_as_float(v.u & 0xFFFF0000u);   // exact
    union { float f; unsigned u; } w; w.f = res;
    return (u16)(w.u >> 16);
}
__device__ __forceinline__ float bf2f(u16 x) {
    union { unsigned u; float f; } v; v.u = ((unsigned)x) << 16;
    return v.f;
}
// Relaxed agent-scope atomics: MALL-coherent, no cache maintenance per op.
__device__ __forceinline__ float aload_f(const float* p) {
    unsigned v = __hip_atomic_load((const unsigned*)p, __ATOMIC_RELAXED,
                                   __HIP_MEMORY_SCOPE_AGENT);
    return __uint_as_float(v);
}
__device__ __forceinline__ void astore_f(float* p, float x) {
    __hip_atomic_store((unsigned*)p, __float_as_uint(x), __ATOMIC_RELAXED,
                       __HIP_MEMORY_SCOPE_AGENT);
}

// ---------------------------------------------------------------------------
// prep_all: conversions + gathers + W1cat concat + combined bias, one launch.
// ---------------------------------------------------------------------------
__global__ __launch_bounds__(256) void prep_all(
    const float* __restrict__ enc_h, const float* __restrict__ U_a,
    const float* __restrict__ W_ctx, const float* __restrict__ W_emb,
    const float* __restrict__ embed, const int* __restrict__ tw,
    const float* __restrict__ W_hs, const float* __restrict__ W_a,
    const float* __restrict__ W_hzr,
    const float* __restrict__ b_Ua, const float* __restrict__ b_a,
    u16* __restrict__ EHhi, u16* __restrict__ EHlo,
    u16* __restrict__ UAhi, u16* __restrict__ UAlo,
    u16* __restrict__ WChi, u16* __restrict__ WClo,
    u16* __restrict__ WEhi, u16* __restrict__ WElo,
    u16* __restrict__ AGhi, u16* __restrict__ AGlo,
    u16* __restrict__ Whs16, float* __restrict__ W1cat,
    float* __restrict__ bUa2)
{
    const int bid = blockIdx.x, tid = threadIdx.x;
    if (bid < 8192) {                         // enc_h 2048x1024
        int idx = bid * 256 + tid;
        float x = enc_h[idx];
        EHhi[idx] = f_hi_trunc(x); EHlo[idx] = f_lo_trunc(x);
    } else if (bid < 10240) {                 // U_a 1024x512
        int idx = (bid - 8192) * 256 + tid;
        float x = U_a[idx];
        UAhi[idx] = f_hi_trunc(x); UAlo[idx] = f_lo_trunc(x);
    } else if (bid < 16384) {                 // W_ctx 1024x1536
        int idx = (bid - 10240) * 256 + tid;
        float x = W_ctx[idx];
        WChi[idx] = f_hi_trunc(x); WClo[idx] = f_lo_trunc(x);
    } else if (bid < 18304) {                 // W_emb pad 320x1536
        int idx = (bid - 16384) * 256 + tid;
        int r = idx / 1536, c = idx - r * 1536;
        float x = (r < EE) ? W_emb[(size_t)r * 1536 + c] : 0.f;
        WEhi[idx] = f_hi_trunc(x); WElo[idx] = f_lo_trunc(x);
    } else if (bid < 19584) {                 // embed gather 1024x320
        int idx = (bid - 18304) * 256 + tid;
        int r = idx / 320, c = idx - r * 320;
        float x = (c < EE) ? embed[(size_t)tw[r] * EE + c] : 0.f;
        AGhi[idx] = f_hi_trunc(x); AGlo[idx] = f_lo_trunc(x);
    } else if (bid < 20608) {                 // W_hs -> bf16 512x512
        int idx = (bid - 19584) * 256 + tid;
        Whs16[idx] = f2bf(W_hs[idx]);
    } else if (bid < 23680) {                 // W1cat = [W_a | W_hzr] 512x1536
        int idx = (bid - 20608) * 256 + tid;
        int k = idx / 1536, c = idx - k * 1536;
        W1cat[idx] = (c < HH) ? W_a[(size_t)k * HH + c]
                              : W_hzr[(size_t)k * HD2 + (c - HH)];
    } else {                                  // bUa2 = b_Ua + b_a
        int idx = (bid - 23680) * 256 + tid;
        if (idx < HH) bUa2[idx] = b_Ua[idx] + b_a[idx];
    }
}

// ---------------------------------------------------------------------------
// transpose_conv: W_out fp32 [512][32000] -> Wt bf16 [32000][512] (RNE).
// ---------------------------------------------------------------------------
__global__ __launch_bounds__(256) void transpose_conv(
    const float* __restrict__ src, int K, int N, int dld,
    u16* __restrict__ dhi)
{
    __shared__ float t[64][65];
    const int nt = blockIdx.x, ktile = blockIdx.y, tid = threadIdx.x;
    const int n0 = nt * 64, k0 = ktile * 64;
#pragma unroll 4
    for (int i = 0; i < 16; i++) {
        int kr = i * 4 + (tid >> 6);
        int nc = tid & 63;
        t[kr][nc] = src[(size_t)(k0 + kr) * N + n0 + nc];
    }
    __syncthreads();
    const int n = tid >> 2, kc = (tid & 3) * 16;
    unsigned wh[8];
#pragma unroll
    for (int jj = 0; jj < 8; jj++) {
        float x0 = t[kc + 2 * jj][n], x1 = t[kc + 2 * jj + 1][n];
        wh[jj] = (unsigned)f2bf(x0) | ((unsigned)f2bf(x1) << 16);
    }
    u16* dh = dhi + (size_t)(n0 + n) * dld + k0 + kc;
    *(uint4*)(dh)     = (uint4){wh[0], wh[1], wh[2], wh[3]};
    *(uint4*)(dh + 8) = (uint4){wh[4], wh[5], wh[6], wh[7]};
}

// ---------------------------------------------------------------------------
// pre_mfma: C = A @ W + bias via bf16 hi/lo x3 MFMA (fp32-accurate).
// ---------------------------------------------------------------------------
template<int KSTEPS, bool BF16OUT>
__global__ __launch_bounds__(256) void pre_mfma(
    const u16* __restrict__ Ahi, const u16* __restrict__ Alo,
    const u16* __restrict__ Whi, const u16* __restrict__ Wlo,
    const float* __restrict__ bias, void* __restrict__ Cout, int N)
{
    __shared__ u16 ah[256 * 40], al[256 * 40];
    __shared__ u16 bh[64 * 40],  bl[64 * 40];
    const int nb = blockIdx.x, mb = blockIdx.y, tid = threadIdx.x;
    const int w = tid >> 6, ln = tid & 63;
    const int quad = ln >> 4, lm = ln & 15;
    const int n0 = nb * 64;
    const int K = KSTEPS * 32;

    f32x4 acc[4][4];
#pragma unroll
    for (int r = 0; r < 4; r++)
#pragma unroll
        for (int c = 0; c < 4; c++)
            acc[r][c] = (f32x4){0.f, 0.f, 0.f, 0.f};

    for (int kt = 0; kt < KSTEPS; kt++) {
        const int k0 = kt * 32;
        {
            const uint4* sh = (const uint4*)(Ahi + (size_t)(mb * 256 + tid) * K + k0);
            const uint4* sl = (const uint4*)(Alo + (size_t)(mb * 256 + tid) * K + k0);
            uint4 h0 = sh[0], h1 = sh[1], h2 = sh[2], h3 = sh[3];
            uint4 l0 = sl[0], l1 = sl[1], l2 = sl[2], l3 = sl[3];
            uint4* dh = (uint4*)(ah + tid * 40);
            dh[0] = h0; dh[1] = h1; dh[2] = h2; dh[3] = h3;
            uint4* dl = (uint4*)(al + tid * 40);
            dl[0] = l0; dl[1] = l1; dl[2] = l2; dl[3] = l3;
        }
        {
            const int kr = tid >> 3, c8 = (tid & 7) * 8;
            union { uint4 v; u16 u[8]; } uh, ul;
            uh.v = *(const uint4*)(Whi + (size_t)(k0 + kr) * N + n0 + c8);
            ul.v = *(const uint4*)(Wlo + (size_t)(k0 + kr) * N + n0 + c8);
#pragma unroll
            for (int jj = 0; jj < 8; jj++) {
                bh[(c8 + jj) * 40 + kr] = uh.u[jj];
                bl[(c8 + jj) * 40 + kr] = ul.u[jj];
            }
        }
        __syncthreads();
        short8 afh[4], afl[4], bfh[4], bfl[4];
#pragma unroll
        for (int r = 0; r < 4; r++) {
            afh[r] = *(const short8*)(ah + ((w * 4 + r) * 16 + lm) * 40 + quad * 8);
            afl[r] = *(const short8*)(al + ((w * 4 + r) * 16 + lm) * 40 + quad * 8);
        }
#pragma unroll
        for (int c = 0; c < 4; c++) {
            bfh[c] = *(const short8*)(bh + (c * 16 + lm) * 40 + quad * 8);
            bfl[c] = *(const short8*)(bl + (c * 16 + lm) * 40 + quad * 8);
        }
#pragma unroll
        for (int r = 0; r < 4; r++)
#pragma unroll
            for (int c = 0; c < 4; c++) {
                acc[r][c] = __builtin_amdgcn_mfma_f32_16x16x32_bf16(
                    afh[r], bfh[c], acc[r][c], 0, 0, 0);
                acc[r][c] = __builtin_amdgcn_mfma_f32_16x16x32_bf16(
                    afh[r], bfl[c], acc[r][c], 0, 0, 0);
                acc[r][c] = __builtin_amdgcn_mfma_f32_16x16x32_bf16(
                    afl[r], bfh[c], acc[r][c], 0, 0, 0);
            }
        __syncthreads();
    }
#pragma unroll
    for (int r = 0; r < 4; r++) {
        int row = mb * 256 + (w * 4 + r) * 16 + quad * 4;
#pragma unroll
        for (int c = 0; c < 4; c++) {
            int col = n0 + c * 16 + lm;
            float bo = bias[col];
#pragma unroll
            for (int q2 = 0; q2 < 4; q2++) {
                float val = acc[r][c][q2] + bo;
                if (BF16OUT)
                    ((u16*)Cout)[(size_t)(row + q2) * N + col] = f2bf(val);
                else
                    ((float*)Cout)[(size_t)(row + q2) * N + col] = val;
            }
        }
    }
}

// ---------------------------------------------------------------------------
// rnn_persist: entire 32-step recurrence, ONE launch, 256 blocks x 256 thr.
// Block bid: g = bid>>3 (batch), j = bid&7 (slice slot). XCD(bid)=bid%8=j,
// so XCD j only ever touches slice-j weights: W1 rows [64j,64j+64),
// Whs cols [64j,64j+64), Gc col-slices, Uh — total ~3.3 MB, L2-resident.
// 2 per-group (8-block) barriers/step; monotonic relaxed-atomic counter;
// cross-block data (parts, rs) via MALL-routed relaxed atomics. s-slice
// stays in LDS (block j finalizes exactly the k-slice its phase A needs).
// ---------------------------------------------------------------------------
__global__ __launch_bounds__(256) void rnn_persist(
    const float* __restrict__ W1cat,     // [512][1536] fp32
    const u16* __restrict__ Uh16,        // [32*64][512] (b_Ua+b_a baked)
    const u16* __restrict__ Gc16,        // [32*64][1536] (b_ctx baked)
    const float* __restrict__ Ge,        // [1024][1536] (b_emb baked)
    const u16* __restrict__ Whs16,       // [512][512] bf16
    const float* __restrict__ b_hzr, const float* __restrict__ b_hs,
    const float* __restrict__ v_w, const float* __restrict__ v_b,
    const float* __restrict__ prev_s,
    float* __restrict__ parts,           // [32][8][1536]
    float* __restrict__ rsx,             // [32][512]
    u16* __restrict__ sqh, u16* __restrict__ sql,
    unsigned* __restrict__ bars)
{
    const int bid = blockIdx.x, tid = threadIdx.x;
    const int g = bid >> 3, j = bid & 7;
    const int ln = tid & 63, w = tid >> 6;
    const int c64 = tid & 63, role = tid >> 6;

    __shared__ float s_own[64];
    __shared__ float outs_lds[HH];
    __shared__ float zr_lds[128];        // [0..64)=z presum, [64..128)=r presum
    __shared__ float red[256];
    __shared__ float attn_s[LLn];
    __shared__ float zb_lds[64], pst_lds[64];
    __shared__ float rs_lds[HH];

    unsigned* bar = bars + g * 64;
    unsigned tgt = 0;

    float* pg = parts + ((size_t)g * 8 + j) * HD3;
    const float* pr = parts + (size_t)g * 8 * HD3;
    float* rg = rsx + (size_t)g * HH;

    // per-lane invariants
    float vw_r[8];
    {
        float4 v0 = *(const float4*)(v_w + ln * 8);
        float4 v1 = *(const float4*)(v_w + ln * 8 + 4);
        vw_r[0]=v0.x; vw_r[1]=v0.y; vw_r[2]=v0.z; vw_r[3]=v0.w;
        vw_r[4]=v1.x; vw_r[5]=v1.y; vw_r[6]=v1.z; vw_r[7]=v1.w;
    }
    const float vb = v_b[0];

    if (tid < 64) s_own[tid] = prev_s[(size_t)g * HH + j * 64 + tid];
    __syncthreads();

    for (int t = 0; t < TT; t++) {
        // ===== phase A: k-slice partials (exact fp32) =====
        {
            float a0=0.f, a1=0.f, a2=0.f, a3=0.f, a4=0.f, a5=0.f;
            const float* wb = W1cat + (size_t)(j * 64) * HD3 + tid;
#pragma unroll 4
            for (int k = 0; k < 64; k++) {
                float sv = s_own[k];
                const float* wr = wb + (size_t)k * HD3;
                a0 = fmaf(sv, wr[0],    a0);
                a1 = fmaf(sv, wr[256],  a1);
                a2 = fmaf(sv, wr[512],  a2);
                a3 = fmaf(sv, wr[768],  a3);
                a4 = fmaf(sv, wr[1024], a4);
                a5 = fmaf(sv, wr[1280], a5);
            }
            astore_f(&pg[tid],        a0);
            astore_f(&pg[tid + 256],  a1);
            astore_f(&pg[tid + 512],  a2);
            astore_f(&pg[tid + 768],  a3);
            astore_f(&pg[tid + 1024], a4);
            astore_f(&pg[tid + 1280], a5);
        }
        // barrier 1
        asm volatile("s_waitcnt vmcnt(0)" ::: "memory");
        __syncthreads();
        tgt += 8;
        if (tid == 0) {
            __hip_atomic_fetch_add(bar, 1u, __ATOMIC_RELAXED, __HIP_MEMORY_SCOPE_AGENT);
            while (__hip_atomic_load(bar, __ATOMIC_RELAXED, __HIP_MEMORY_SCOPE_AGENT) < tgt)
                __builtin_amdgcn_s_sleep(1);
        }
        __syncthreads();

        // ===== B1: sum partials, scores, softmax, own gates, rs =====
        {
            float o0 = 0.f, o1 = 0.f;
#pragma unroll
            for (int p = 0; p < 8; p++) {
                o0 += aload_f(&pr[(size_t)p * HD3 + tid]);
                o1 += aload_f(&pr[(size_t)p * HD3 + tid + 256]);
            }
            outs_lds[tid]       = o0;
            outs_lds[tid + 256] = o1;
            if (role == 0) {
                float zs = 0.f;
#pragma unroll
                for (int p = 0; p < 8; p++)
                    zs += aload_f(&pr[(size_t)p * HD3 + HH + j * 64 + c64]);
                zr_lds[c64] = zs;
            } else if (role == 1) {
                float rs_ = 0.f;
#pragma unroll
                for (int p = 0; p < 8; p++)
                    rs_ += aload_f(&pr[(size_t)p * HD3 + HD2 + j * 64 + c64]);
                zr_lds[64 + c64] = rs_;
            }
        }
        __syncthreads();

        // scores (redundant across group): wave w -> l = w*16+lt
        {
            float o_r[8];
            float4 q0 = *(const float4*)(outs_lds + ln * 8);
            float4 q1 = *(const float4*)(outs_lds + ln * 8 + 4);
            o_r[0]=q0.x; o_r[1]=q0.y; o_r[2]=q0.z; o_r[3]=q0.w;
            o_r[4]=q1.x; o_r[5]=q1.y; o_r[6]=q1.z; o_r[7]=q1.w;
            for (int lt = 0; lt < 16; lt++) {
                const int l = w * 16 + lt;
                uint4 uv = *(const uint4*)(Uh16 + ((size_t)(g * LLn + l)) * HH + ln * 8);
                float acc;
                acc = fast_tanh(o_r[0] + __uint_as_float(uv.x << 16)) * vw_r[0];
                acc = fmaf(fast_tanh(o_r[1] + __uint_as_float(uv.x & 0xFFFF0000u)), vw_r[1], acc);
                acc = fmaf(fast_tanh(o_r[2] + __uint_as_float(uv.y << 16)),          vw_r[2], acc);
                acc = fmaf(fast_tanh(o_r[3] + __uint_as_float(uv.y & 0xFFFF0000u)), vw_r[3], acc);
                acc = fmaf(fast_tanh(o_r[4] + __uint_as_float(uv.z << 16)),          vw_r[4], acc);
                acc = fmaf(fast_tanh(o_r[5] + __uint_as_float(uv.z & 0xFFFF0000u)), vw_r[5], acc);
                acc = fmaf(fast_tanh(o_r[6] + __uint_as_float(uv.w << 16)),          vw_r[6], acc);
                acc = fmaf(fast_tanh(o_r[7] + __uint_as_float(uv.w & 0xFFFF0000u)), vw_r[7], acc);
                for (int o = 32; o > 0; o >>= 1) acc += __shfl_xor(acc, o);
                if (ln == 0) red[l] = acc;
            }
        }
        __syncthreads();
        if (tid < 64) {
            float v = red[tid] + vb;
            float m = v;
            for (int o = 32; o > 0; o >>= 1) m = fmaxf(m, __shfl_xor(m, o));
            float e = __expf(v - m);
            float s = e;
            for (int o = 32; o > 0; o >>= 1) s += __shfl_xor(s, o);
            attn_s[tid] = e / s;
        }
        __syncthreads();

        // own-slice gates: role 0 -> z, role 1 -> r+rs, role 2 -> pst
        if (role < 3) {
            const int col = role * HH + j * 64 + c64;
            const u16* gcb = Gc16 + (size_t)g * LLn * HD3 + col;
            float acc = 0.f;
#pragma unroll 4
            for (int l = 0; l < LLn; l++)
                acc = fmaf(attn_s[l], bf2f(gcb[(size_t)l * HD3]), acc);
            const float* ge = Ge + ((size_t)(g * TT + t)) * HD3;
            if (role == 0) {
                zb_lds[c64] = fast_sigmoid(zr_lds[c64] + acc + ge[col]
                                           + b_hzr[j * 64 + c64]);
            } else if (role == 1) {
                float r = fast_sigmoid(zr_lds[64 + c64] + acc + ge[col]
                                       + b_hzr[HH + j * 64 + c64]);
                astore_f(&rg[j * 64 + c64], r * s_own[c64]);
            } else {
                pst_lds[c64] = acc + ge[col] + b_hs[j * 64 + c64];
            }
        }
        // barrier 2
        asm volatile("s_waitcnt vmcnt(0)" ::: "memory");
        __syncthreads();
        tgt += 8;
        if (tid == 0) {
            __hip_atomic_fetch_add(bar, 1u, __ATOMIC_RELAXED, __HIP_MEMORY_SCOPE_AGENT);
            while (__hip_atomic_load(bar, __ATOMIC_RELAXED, __HIP_MEMORY_SCOPE_AGENT) < tgt)
                __builtin_amdgcn_s_sleep(1);
        }
        __syncthreads();

        // ===== B2: gemm2 own cols + finalize =====
        rs_lds[tid]       = aload_f(&rg[tid]);
        rs_lds[tid + 256] = aload_f(&rg[tid + 256]);
        __syncthreads();
        {
            const int q = role;                     // k-quarter
            const u16* wp = Whs16 + (size_t)(q * 128) * HH + j * 64 + c64;
            const float* rp = rs_lds + q * 128;
            float a0 = 0.f, a1 = 0.f, a2 = 0.f, a3 = 0.f;
#pragma unroll 4
            for (int k = 0; k < 128; k += 4) {
                a0 = fmaf(rp[k + 0], bf2f(wp[(size_t)(k + 0) * HH]), a0);
                a1 = fmaf(rp[k + 1], bf2f(wp[(size_t)(k + 1) * HH]), a1);
                a2 = fmaf(rp[k + 2], bf2f(wp[(size_t)(k + 2) * HH]), a2);
                a3 = fmaf(rp[k + 3], bf2f(wp[(size_t)(k + 3) * HH]), a3);
            }
            red[tid] = (a0 + a1) + (a2 + a3);
        }
        __syncthreads();
        if (tid < 64) {
            float g2 = red[tid] + red[64 + tid] + red[128 + tid] + red[192 + tid];
            float st = fast_tanh(pst_lds[tid] + g2);
            float sv = s_own[tid];
            float sn = fmaf(zb_lds[tid], st - sv, sv);
            s_own[tid] = sn;
            size_t off = ((size_t)(g * TT + t)) * HH + j * 64 + tid;
            sqh[off] = f_hi_trunc(sn);
            sql[off] = f_lo_trunc(sn);
        }
        __syncthreads();
    }
}

// ---------------------------------------------------------------------------
// final_gemm: out[1024 x 32000] = s_seq(hi/lo bf16) @ Wt^T + b_out.
// Round-2 proven structure: grid (500 nb, 4 mb) = 2000 blocks, 256x64 tile,
// A hi/lo staged in LDS per kt, B linear-copied from pre-transposed Wt.
// ---------------------------------------------------------------------------
__global__ __launch_bounds__(256) void final_gemm(
    const u16* __restrict__ Ahi, const u16* __restrict__ Alo,
    const u16* __restrict__ Wt, const float* __restrict__ b_out,
    float* __restrict__ out)
{
    __shared__ u16 ah_lds[256 * 40];
    __shared__ u16 al_lds[256 * 40];
    __shared__ u16 b_lds[64 * 40];
    const int nb = blockIdx.x, mb = blockIdx.y, tid = threadIdx.x;
    const int w = tid >> 6, ln = tid & 63;
    const int quad = ln >> 4, lm = ln & 15;
    const int n0 = nb * 64;

    f32x4 acc[4][4];
#pragma unroll
    for (int r = 0; r < 4; r++)
#pragma unroll
        for (int c = 0; c < 4; c++)
            acc[r][c] = (f32x4){0.f, 0.f, 0.f, 0.f};

    for (int kt = 0; kt < 16; kt++) {
        const int k0 = kt * 32;
        {   // stage A hi+lo
            const uint4* sh = (const uint4*)(Ahi + (size_t)(mb * 256 + tid) * HH + k0);
            const uint4* sl = (const uint4*)(Alo + (size_t)(mb * 256 + tid) * HH + k0);
            uint4 h0 = sh[0], h1 = sh[1], h2 = sh[2], h3 = sh[3];
            uint4 l0 = sl[0], l1 = sl[1], l2 = sl[2], l3 = sl[3];
            uint4* dh = (uint4*)(ah_lds + tid * 40);
            dh[0] = h0; dh[1] = h1; dh[2] = h2; dh[3] = h3;
            uint4* dl = (uint4*)(al_lds + tid * 40);
            dl[0] = l0; dl[1] = l1; dl[2] = l2; dl[3] = l3;
        }
        {   // stage B: linear copy (thread tid: n = tid>>2, part = tid&3)
            const int n = tid >> 2, part = tid & 3;
            uint4 v = *(const uint4*)(Wt + (size_t)(n0 + n) * HH + k0 + part * 8);
            *(uint4*)(b_lds + n * 40 + part * 8) = v;
        }
        __syncthreads();
        short8 afh[4], afl[4], bq[4];
#pragma unroll
        for (int r = 0; r < 4; r++) {
            afh[r] = *(const short8*)(ah_lds + ((w * 4 + r) * 16 + lm) * 40 + quad * 8);
            afl[r] = *(const short8*)(al_lds + ((w * 4 + r) * 16 + lm) * 40 + quad * 8);
        }
#pragma unroll
        for (int c = 0; c < 4; c++)
            bq[c] = *(const short8*)(b_lds + (c * 16 + lm) * 40 + quad * 8);
#pragma unroll
        for (int r = 0; r < 4; r++)
#pragma unroll
            for (int c = 0; c < 4; c++) {
                acc[r][c] = __builtin_amdgcn_mfma_f32_16x16x32_bf16(
                    afh[r], bq[c], acc[r][c], 0, 0, 0);
                acc[r][c] = __builtin_amdgcn_mfma_f32_16x16x32_bf16(
                    afl[r], bq[c], acc[r][c], 0, 0, 0);
            }
        __syncthreads();
    }
#pragma unroll
    for (int r = 0; r < 4; r++) {
        int row = mb * 256 + (w * 4 + r) * 16 + quad * 4;
#pragma unroll
        for (int c = 0; c < 4; c++) {
            int col = n0 + c * 16 + lm;
            float bo = b_out[col];
#pragma unroll
            for (int qq = 0; qq < 4; qq++)
                out[(size_t)(row + qq) * VV + col] = acc[r][c][qq] + bo;
        }
    }
}

// ---------------------------------------------------------------------------
extern "C" void kernel_launch(void* const* d_in, const int* in_sizes, int n_in,
                              void* d_out, int out_size, void* d_ws, size_t ws_size,
                              hipStream_t stream)
{
    const float* enc_h  = (const float*)d_in[0];
    const float* prev_s = (const float*)d_in[1];
    const int*   tw     = (const int*)  d_in[2];
    const float* embed  = (const float*)d_in[3];
    const float* W_a    = (const float*)d_in[4];
    const float* b_a    = (const float*)d_in[5];
    const float* U_a    = (const float*)d_in[6];
    const float* b_Ua   = (const float*)d_in[7];
    const float* v_w    = (const float*)d_in[8];
    const float* v_b    = (const float*)d_in[9];
    const float* W_emb  = (const float*)d_in[10];
    const float* b_emb  = (const float*)d_in[11];
    const float* W_hzr  = (const float*)d_in[12];
    const float* b_hzr  = (const float*)d_in[13];
    const float* W_hs   = (const float*)d_in[14];
    const float* b_hs   = (const float*)d_in[15];
    const float* W_ctx  = (const float*)d_in[16];
    const float* b_ctx  = (const float*)d_in[17];
    const float* W_out  = (const float*)d_in[18];
    const float* b_out  = (const float*)d_in[19];
    float* out = (float*)d_out;

    float* ws = (float*)d_ws;
    unsigned* bars = (unsigned*)ws;  ws += 2048;     // 32 groups x 64 u32
    float* Ge     = ws;  ws += 1024 * 1536;
    float* W1cat  = ws;  ws += 512 * 1536;
    float* parts  = ws;  ws += 32 * 8 * 1536;
    float* rsx    = ws;  ws += 32 * 512;
    float* bUa2   = ws;  ws += 512;
    u16* Uh16 = (u16*)ws;  ws += (2048 * 512) / 2;
    u16* Gc16 = (u16*)ws;  ws += (2048 * 1536) / 2;
    u16* sqh  = (u16*)ws;  ws += (1024 * 512) / 2;
    u16* sql  = (u16*)ws;  ws += (1024 * 512) / 2;
    u16* EHhi = (u16*)ws;  ws += (2048 * 1024) / 2;
    u16* EHlo = (u16*)ws;  ws += (2048 * 1024) / 2;
    u16* UAhi = (u16*)ws;  ws += (1024 * 512) / 2;
    u16* UAlo = (u16*)ws;  ws += (1024 * 512) / 2;
    u16* WChi = (u16*)ws;  ws += (1024 * 1536) / 2;
    u16* WClo = (u16*)ws;  ws += (1024 * 1536) / 2;
    u16* WEhi = (u16*)ws;  ws += (320 * 1536) / 2;
    u16* WElo = (u16*)ws;  ws += (320 * 1536) / 2;
    u16* AGhi = (u16*)ws;  ws += (1024 * 320) / 2;
    u16* AGlo = (u16*)ws;  ws += (1024 * 320) / 2;
    u16* Wt   = (u16*)ws;  ws += (32000 * 512) / 2;
    u16* Whs16= (u16*)ws;  ws += (512 * 512) / 2;

    hipMemsetAsync(bars, 0, 8192, stream);

    prep_all<<<dim3(23682), 256, 0, stream>>>(
        enc_h, U_a, W_ctx, W_emb, embed, tw, W_hs, W_a, W_hzr, b_Ua, b_a,
        EHhi, EHlo, UAhi, UAlo, WChi, WClo, WEhi, WElo, AGhi, AGlo,
        Whs16, W1cat, bUa2);

    transpose_conv<<<dim3(500, 8), 256, 0, stream>>>(W_out, 512, 32000, 512, Wt);

    pre_mfma<32, true ><<<dim3(8, 8),  256, 0, stream>>>(EHhi, EHlo, UAhi, UAlo, bUa2,  Uh16, 512);
    pre_mfma<32, true ><<<dim3(24, 8), 256, 0, stream>>>(EHhi, EHlo, WChi, WClo, b_ctx, Gc16, 1536);
    pre_mfma<10, false><<<dim3(24, 4), 256, 0, stream>>>(AGhi, AGlo, WEhi, WElo, b_emb, Ge,   1536);

    rnn_persist<<<dim3(256), 256, 0, stream>>>(
        W1cat, Uh16, Gc16, Ge, Whs16,
        b_hzr, b_hs, v_w, v_b, prev_s,
        parts, rsx, sqh, sql, bars);

    final_gemm<<<dim3(500, 4), 256, 0, stream>>>(sqh, sql, Wt, b_out, out);
}